// Round 4
// baseline (222.383 us; speedup 1.0000x reference)
//
#include <hip/hip_runtime.h>

typedef __attribute__((ext_vector_type(8))) short          bf16x8;
typedef __attribute__((ext_vector_type(8))) unsigned short u16x8;
typedef __attribute__((ext_vector_type(4))) float          f32x4;
typedef __attribute__((ext_vector_type(4))) int            i32x4;
typedef __attribute__((ext_vector_type(4))) unsigned int   u32x4;

union U8 { u16x8 u; bf16x8 b; u32x4 w; };

__device__ __forceinline__ unsigned short f2bf(float f){
  unsigned u = __float_as_uint(f);
  return (unsigned short)((u + 0x7fffu + ((u >> 16) & 1u)) >> 16);
}
// pack two floats to bf16x2 (round-half-up): lo->low16, hi->high16. exact 0 preserved.
__device__ __forceinline__ unsigned pack_bf16(float lo, float hi){
  unsigned a = __float_as_uint(hi) + 0x8000u;
  unsigned b = __float_as_uint(lo) + 0x8000u;
  return __builtin_amdgcn_perm(a, b, 0x07060302u);
}

#define NN  1024
#define FIN 256
#define NH  8
#define FO  64

// ---------------------------------------------------------------------------
// Stage 0: recx = x*Np*e_at (bf16);  wB[h,o,f] = w[h,f,o] (bf16)
// ---------------------------------------------------------------------------
__global__ __launch_bounds__(256) void stage0(
    const float* __restrict__ x, const float* __restrict__ e_at,
    const float* __restrict__ Np, const float* __restrict__ w,
    unsigned short* __restrict__ recx, unsigned short* __restrict__ wB)
{
  const int tid = blockIdx.x * 256 + threadIdx.x;
  const int nthr = gridDim.x * 256;
  for (int g = tid; g < 262144; g += nthr){          // 2M elems / 8
    const int f8 = (g & 31) * 8;
    const int n  = (g >> 5) & 1023;
    const int b  = g >> 15;
    const float* ep = e_at + (b * NN + n) * FIN + f8;
    const float* qp = Np + n * FIN + f8;
    const float* xp = x + b * FIN + f8;
    f32x4 e0 = *(const f32x4*)ep, e1 = *(const f32x4*)(ep + 4);
    f32x4 q0 = *(const f32x4*)qp, q1 = *(const f32x4*)(qp + 4);
    f32x4 x0 = *(const f32x4*)xp, x1 = *(const f32x4*)(xp + 4);
    u16x8 r;
    #pragma unroll
    for (int j = 0; j < 4; j++){
      r[j]     = f2bf(e0[j] * q0[j] * x0[j]);
      r[j + 4] = f2bf(e1[j] * q1[j] * x1[j]);
    }
    *(u16x8*)(recx + g * 8) = r;
  }
  for (int i = tid; i < 131072; i += nthr){          // w transpose
    const int o = i & 63, f = (i >> 6) & 255, h = i >> 14;
    wB[h * 16384 + o * FIN + f] = f2bf(w[i]);
  }
}

// ---------------------------------------------------------------------------
// Stage A: h = recx @ w per head (MFMA); hT[b,h,o,n] bf16 (coalesced via LDS
// transpose); emits exp tables e^s, e^{0.2s}, e^d, e^{0.2d}.
// grid (8 h, 16 n-tiles(64), 8 b), block 256.
// ---------------------------------------------------------------------------
__global__ __launch_bounds__(256, 4) void stageA(
    const unsigned short* __restrict__ recx,
    const unsigned short* __restrict__ wB,
    const float* __restrict__ a_src, const float* __restrict__ a_dst,
    unsigned short* __restrict__ hT,
    float* __restrict__ exps, float* __restrict__ exps2,
    float* __restrict__ expd, float* __restrict__ expd2)
{
  __shared__ unsigned short tbuf[64 * 72];
  const int t = threadIdx.x;
  const int h = blockIdx.x, n0 = blockIdx.y * 64, b = blockIdx.z;
  const int wave = t >> 6, lane = t & 63, quad = lane >> 4, l15 = lane & 15;
  const int nrow = n0 + 16 * wave + l15;

  const unsigned short* ap = recx + (b * NN + nrow) * FIN + quad * 8;
  const unsigned short* wp = wB + h * 16384 + l15 * FIN + quad * 8;

  U8 afr[8];
  #pragma unroll
  for (int kc = 0; kc < 8; kc++) afr[kc].u = *(const u16x8*)(ap + kc * 32);

  f32x4 acc[4] = {};
  #pragma unroll
  for (int kc = 0; kc < 8; kc++){
    U8 bf[4];
    #pragma unroll
    for (int ss = 0; ss < 4; ss++) bf[ss].u = *(const u16x8*)(wp + ss * 4096 + kc * 32);
    #pragma unroll
    for (int ss = 0; ss < 4; ss++)
      acc[ss] = __builtin_amdgcn_mfma_f32_16x16x32_bf16(afr[kc].b, bf[ss].b, acc[ss], 0, 0, 0);
  }

  // C/D: col(o)=l15, row(n)=quad*4+i.  LDS transpose -> coalesced hT stores.
  #pragma unroll
  for (int ss = 0; ss < 4; ss++)
    #pragma unroll
    for (int i = 0; i < 4; i++)
      tbuf[(16 * ss + l15) * 72 + 16 * wave + quad * 4 + i] = f2bf(acc[ss][i]);
  __syncthreads();
  {
    const int o = t >> 2, c0 = (t & 3) * 16;
    unsigned short* dst = hT + ((b * NH + h) * FO + o) * NN + n0 + c0;
    *(u16x8*)(dst)     = *(const u16x8*)(tbuf + o * 72 + c0);
    *(u16x8*)(dst + 8) = *(const u16x8*)(tbuf + o * 72 + c0 + 8);
  }

  // s = h.a_src, d = h.a_dst, then exp tables
  float as4[4], ad4[4];
  #pragma unroll
  for (int ss = 0; ss < 4; ss++){
    as4[ss] = a_src[h * FO + 16 * ss + l15];
    ad4[ss] = a_dst[h * FO + 16 * ss + l15];
  }
  #pragma unroll
  for (int i = 0; i < 4; i++){
    float ps = 0.f, pd = 0.f;
    #pragma unroll
    for (int ss = 0; ss < 4; ss++){ ps += acc[ss][i] * as4[ss]; pd += acc[ss][i] * ad4[ss]; }
    #pragma unroll
    for (int off = 1; off < 16; off <<= 1){
      ps += __shfl_xor(ps, off);
      pd += __shfl_xor(pd, off);
    }
    if (l15 == 0){
      const int idx = (b * NH + h) * NN + n0 + 16 * wave + quad * 4 + i;
      exps [idx] = __expf(ps);
      exps2[idx] = __expf(0.2f * ps);
      expd [idx] = __expf(pd);
      expd2[idx] = __expf(0.2f * pd);
    }
  }
}

// ---------------------------------------------------------------------------
// Stage B: fused masked-softmax aggregation, transcendental-free inner loop.
//   e = adj ? ( Es*Ed > 1 ? Es*Ed : Es2*Ed2 ) : 0     (== exp(leaky(s+d)))
// grid (64 n-tiles(16), 8 b) = 512 blocks, block 512 (8 waves = 8 heads).
// 2 blocks/CU -> 16 waves/CU.
// ---------------------------------------------------------------------------
__global__ __launch_bounds__(512, 4) void stageB(
    const int* __restrict__ A,
    const unsigned short* __restrict__ hT,
    const float* __restrict__ exps, const float* __restrict__ exps2,
    const float* __restrict__ expd, const float* __restrict__ expd2,
    const float* __restrict__ bias, const float* __restrict__ mz,
    float* __restrict__ out)
{
  __shared__ float l_l[NH * 16];
  __shared__ float oacc[16 * FO];
  const int t = threadIdx.x, b = blockIdx.y, n0 = blockIdx.x * 16;
  const int h = t >> 6, lane = t & 63, quad = lane >> 4, l15 = lane & 15;
  const int row = n0 + l15;

  for (int i = t; i < 1024; i += 512) oacc[i] = 0.f;
  __syncthreads();

  const int hb = (b * NH + h) * NN;
  const float Es  = exps [hb + row];
  const float Es2 = exps2[hb + row];
  const int* Ab = A + (b * NN + row) * NN + quad * 8;
  const float* edp = expd  + hb + quad * 8;
  const float* e2p = expd2 + hb + quad * 8;
  const unsigned short* hTb = hT + (b * NH + h) * FO * NN;

  // prefetch chunk 0
  i32x4 a0 = *(const i32x4*)Ab, a1 = *(const i32x4*)(Ab + 4);
  f32x4 ed0 = *(const f32x4*)edp, ed1 = *(const f32x4*)(edp + 4);
  f32x4 e20 = *(const f32x4*)e2p, e21 = *(const f32x4*)(e2p + 4);
  U8 bfr[4];
  #pragma unroll
  for (int ss = 0; ss < 4; ss++)
    bfr[ss].u = *(const u16x8*)(hTb + (16 * ss + l15) * NN + quad * 8);

  float lp = 0.f;
  f32x4 acc[4] = {};

  for (int mc = 0; mc < NN; mc += 32){
    const i32x4 ca0 = a0, ca1 = a1;
    const f32x4 cd0 = ed0, cd1 = ed1, c20 = e20, c21 = e21;
    U8 cb[4];
    #pragma unroll
    for (int ss = 0; ss < 4; ss++) cb[ss] = bfr[ss];
    if (mc + 32 < NN){
      a0  = *(const i32x4*)(Ab + mc + 32);  a1  = *(const i32x4*)(Ab + mc + 36);
      ed0 = *(const f32x4*)(edp + mc + 32); ed1 = *(const f32x4*)(edp + mc + 36);
      e20 = *(const f32x4*)(e2p + mc + 32); e21 = *(const f32x4*)(e2p + mc + 36);
      #pragma unroll
      for (int ss = 0; ss < 4; ss++)
        bfr[ss].u = *(const u16x8*)(hTb + (16 * ss + l15) * NN + mc + 32 + quad * 8);
    }
    U8 p;
    #pragma unroll
    for (int r = 0; r < 4; r++){
      const int j0 = 2 * r, j1 = 2 * r + 1;
      const float d1v = (j0 < 4) ? cd0[j0] : cd1[j0 - 4];
      const float d2v = (j0 < 4) ? c20[j0] : c21[j0 - 4];
      const int   av  = (j0 < 4) ? ca0[j0] : ca1[j0 - 4];
      const float d1w = (j1 < 4) ? cd0[j1] : cd1[j1 - 4];
      const float d2w = (j1 < 4) ? c20[j1] : c21[j1 - 4];
      const int   aw  = (j1 < 4) ? ca0[j1] : ca1[j1 - 4];
      const float x1 = Es * d1v, y1 = Es2 * d2v;
      float e0 = (x1 > 1.f) ? x1 : y1;
      e0 = (av > 0) ? e0 : 0.f;
      const float x2 = Es * d1w, y2 = Es2 * d2w;
      float e1 = (x2 > 1.f) ? x2 : y2;
      e1 = (aw > 0) ? e1 : 0.f;
      lp += e0 + e1;
      p.w[r] = pack_bf16(e0, e1);
    }
    #pragma unroll
    for (int ss = 0; ss < 4; ss++)
      acc[ss] = __builtin_amdgcn_mfma_f32_16x16x32_bf16(p.b, cb[ss].b, acc[ss], 0, 0, 0);
  }

  // full row sums: reduce over the 4 quads (cols) of each row
  lp += __shfl_xor(lp, 16);
  lp += __shfl_xor(lp, 32);
  if (lane < 16) l_l[h * 16 + lane] = lp;   // wave-private slice, in-order DS

  float inv[4];
  #pragma unroll
  for (int i = 0; i < 4; i++)
    inv[i] = 0.125f / l_l[h * 16 + quad * 4 + i];

  // normalize + head-sum into oacc.  C/D: row = quad*4+i, col(o) = ss*16+l15
  #pragma unroll
  for (int ss = 0; ss < 4; ss++)
    #pragma unroll
    for (int i = 0; i < 4; i++)
      atomicAdd(&oacc[(quad * 4 + i) * FO + ss * 16 + l15], acc[ss][i] * inv[i]);
  __syncthreads();

  for (int i = t; i < 1024; i += 512){
    const int r = i >> 6, o = i & 63;
    out[(b * NN + n0 + r) * FO + o] = (oacc[i] + bias[o]) * mz[b * NN + n0 + r];
  }
}

extern "C" void kernel_launch(void* const* d_in, const int* in_sizes, int n_in,
                              void* d_out, int out_size, void* d_ws, size_t ws_size,
                              hipStream_t stream)
{
  (void)in_sizes; (void)n_in; (void)out_size; (void)ws_size;
  const float* x    = (const float*)d_in[0];
  const int*   A    = (const int*)d_in[1];
  const float* mz   = (const float*)d_in[2];
  const float* e_at = (const float*)d_in[4];
  const float* Np   = (const float*)d_in[5];
  const float* w    = (const float*)d_in[6];
  const float* asrc = (const float*)d_in[7];
  const float* adst = (const float*)d_in[8];
  const float* bias = (const float*)d_in[9];
  float* out = (float*)d_out;

  char* ws = (char*)d_ws;
  unsigned short* recx = (unsigned short*)ws;                      // 4 MB
  unsigned short* wBuf = (unsigned short*)(ws + 4194304);          // 256 KB
  unsigned short* hT   = (unsigned short*)(ws + 4456448);          // 8 MB
  float* exps  = (float*)(ws + 12845056);                          // 256 KB
  float* exps2 = (float*)(ws + 13107200);                          // 256 KB
  float* expd  = (float*)(ws + 13369344);                          // 256 KB
  float* expd2 = (float*)(ws + 13631488);                          // 256 KB

  stage0<<<dim3(1024), dim3(256), 0, stream>>>(x, e_at, Np, w, recx, wBuf);
  stageA<<<dim3(8, 16, 8), dim3(256), 0, stream>>>(recx, wBuf, asrc, adst, hT,
                                                   exps, exps2, expd, expd2);
  stageB<<<dim3(64, 8), dim3(512), 0, stream>>>(A, hT, exps, exps2, expd, expd2,
                                                bias, mz, out);
}

// Round 5
// 175.235 us; speedup vs baseline: 1.2691x; 1.2691x over previous
//
#include <hip/hip_runtime.h>

typedef __attribute__((ext_vector_type(8))) short          bf16x8;
typedef __attribute__((ext_vector_type(8))) unsigned short u16x8;
typedef __attribute__((ext_vector_type(4))) unsigned short u16x4;
typedef __attribute__((ext_vector_type(4))) float          f32x4;
typedef __attribute__((ext_vector_type(4))) unsigned int   u32x4;

union U8 { u16x8 u; bf16x8 b; u32x4 w; };
union U4 { u16x4 u; unsigned w[2]; };

__device__ __forceinline__ unsigned short f2bf(float f){
  unsigned u = __float_as_uint(f);
  return (unsigned short)((u + 0x7fffu + ((u >> 16) & 1u)) >> 16);
}
// pack two floats to bf16x2 (round-half-up): lo->low16, hi->high16. exact 0 preserved.
__device__ __forceinline__ unsigned pack_bf16(float lo, float hi){
  unsigned a = __float_as_uint(hi) + 0x8000u;
  unsigned b = __float_as_uint(lo) + 0x8000u;
  return __builtin_amdgcn_perm(a, b, 0x07060302u);
}

#define NN  1024
#define FIN 256
#define NH  8
#define FO  64

// ---------------------------------------------------------------------------
// Stage 0: recx = bf16(x*Np*e_at); wB[h,o,f] = bf16(w[h,f,o]);
//          Abits = ballot-packed adjacency (1 bit per edge).
// grid 1024 x 256
// ---------------------------------------------------------------------------
__global__ __launch_bounds__(256) void stage0(
    const float* __restrict__ x, const float* __restrict__ e_at,
    const float* __restrict__ Np, const float* __restrict__ w,
    const int* __restrict__ A,
    unsigned short* __restrict__ recx, unsigned short* __restrict__ wB,
    unsigned long long* __restrict__ Abits)
{
  const int tid = blockIdx.x * 256 + threadIdx.x;   // 262144 threads
  {                                                  // recx: one 8-group each
    const int g = tid;
    const int f8 = (g & 31) * 8;
    const int n  = (g >> 5) & 1023;
    const int b  = g >> 15;
    const float* ep = e_at + (b * NN + n) * FIN + f8;
    const float* qp = Np + n * FIN + f8;
    const float* xp = x + b * FIN + f8;
    f32x4 e0 = *(const f32x4*)ep, e1 = *(const f32x4*)(ep + 4);
    f32x4 q0 = *(const f32x4*)qp, q1 = *(const f32x4*)(qp + 4);
    f32x4 x0 = *(const f32x4*)xp, x1 = *(const f32x4*)(xp + 4);
    u16x8 r;
    #pragma unroll
    for (int j = 0; j < 4; j++){
      r[j]     = f2bf(e0[j] * q0[j] * x0[j]);
      r[j + 4] = f2bf(e1[j] * q1[j] * x1[j]);
    }
    *(u16x8*)(recx + g * 8) = r;
  }
  if (tid < 131072){                                 // w transpose
    const int o = tid & 63, f = (tid >> 6) & 255, h = tid >> 14;
    wB[h * 16384 + o * FIN + f] = f2bf(w[tid]);
  }
  for (int i = tid; i < 8388608; i += 262144){       // adjacency bit-pack
    unsigned long long m = __ballot(A[i] > 0);
    if ((threadIdx.x & 63) == 0) Abits[i >> 6] = m;
  }
}

// ---------------------------------------------------------------------------
// Stage A: h = recx @ w (MFMA). Writes hT panels [b,h,mtile,o(64),32] bf16
// directly from C-frags (no LDS, no barrier) + exp tables e^s,e^.2s,e^d,e^.2d.
// grid (32 tiles(32 rows), 8 b), block 512 (8 waves = 8 heads).
// ---------------------------------------------------------------------------
__global__ __launch_bounds__(512, 2) void stageA(
    const unsigned short* __restrict__ recx,
    const unsigned short* __restrict__ wB,
    const float* __restrict__ a_src, const float* __restrict__ a_dst,
    unsigned short* __restrict__ hT,
    float* __restrict__ exps, float* __restrict__ exps2,
    float* __restrict__ expd, float* __restrict__ expd2)
{
  const int t = threadIdx.x;
  const int n0 = blockIdx.x * 32, b = blockIdx.y;
  const int h = t >> 6, lane = t & 63, quad = lane >> 4, l15 = lane & 15;

  const unsigned short* ap0 = recx + (b * NN + n0 + l15) * FIN + quad * 8;
  const unsigned short* ap1 = ap0 + 16 * FIN;
  const unsigned short* wp  = wB + h * 16384 + l15 * FIN + quad * 8;

  f32x4 acc[2][4] = {};
  #pragma unroll
  for (int kc = 0; kc < 8; kc++){
    U8 a0, a1, bf[4];
    a0.u = *(const u16x8*)(ap0 + kc * 32);
    a1.u = *(const u16x8*)(ap1 + kc * 32);
    #pragma unroll
    for (int ss = 0; ss < 4; ss++) bf[ss].u = *(const u16x8*)(wp + ss * 16 * FIN + kc * 32);
    #pragma unroll
    for (int ss = 0; ss < 4; ss++)
      acc[0][ss] = __builtin_amdgcn_mfma_f32_16x16x32_bf16(a0.b, bf[ss].b, acc[0][ss], 0, 0, 0);
    #pragma unroll
    for (int ss = 0; ss < 4; ss++)
      acc[1][ss] = __builtin_amdgcn_mfma_f32_16x16x32_bf16(a1.b, bf[ss].b, acc[1][ss], 0, 0, 0);
  }

  // Direct panel store: C/D row(n)=quad*4+i, col(o)=16ss+l15.
  // panel element offset: o*32 + n  (n within tile)
  {
    unsigned short* pan = hT + (size_t)(((b * NH + h) * 32 + (n0 >> 5)) * 64) * 32;
    #pragma unroll
    for (int rg = 0; rg < 2; rg++)
      #pragma unroll
      for (int ss = 0; ss < 4; ss++){
        U4 v;
        v.w[0] = pack_bf16(acc[rg][ss][0], acc[rg][ss][1]);
        v.w[1] = pack_bf16(acc[rg][ss][2], acc[rg][ss][3]);
        *(u16x4*)(pan + (16 * ss + l15) * 32 + rg * 16 + quad * 4) = v.u;
      }
  }

  // s = h.a_src, d = h.a_dst -> exp tables
  float as4[4], ad4[4];
  #pragma unroll
  for (int ss = 0; ss < 4; ss++){
    as4[ss] = a_src[h * FO + 16 * ss + l15];
    ad4[ss] = a_dst[h * FO + 16 * ss + l15];
  }
  #pragma unroll
  for (int rg = 0; rg < 2; rg++)
    #pragma unroll
    for (int i = 0; i < 4; i++){
      float ps = 0.f, pd = 0.f;
      #pragma unroll
      for (int ss = 0; ss < 4; ss++){ ps += acc[rg][ss][i] * as4[ss]; pd += acc[rg][ss][i] * ad4[ss]; }
      #pragma unroll
      for (int off = 1; off < 16; off <<= 1){
        ps += __shfl_xor(ps, off);
        pd += __shfl_xor(pd, off);
      }
      if (l15 == 0){
        const int idx = (b * NH + h) * NN + n0 + rg * 16 + quad * 4 + i;
        exps [idx] = __expf(ps);
        exps2[idx] = __expf(0.2f * ps);
        expd [idx] = __expf(pd);
        expd2[idx] = __expf(0.2f * pd);
      }
    }
}

// ---------------------------------------------------------------------------
// Stage B: fused masked-softmax aggregation.
//   e = adj ? max(Es*Ed, Es2*Ed2) : 0        (== exp(leaky_relu(s+d, 0.2)))
//   row-sum l via extra MFMA vs all-ones B (idle matrix pipe).
// grid (32 tiles(32 rows), 8 b) = 256 blocks, block 1024
// (16 waves = 8 heads x 2 row-groups). Only global stream: hT panels (depth-2).
// ---------------------------------------------------------------------------
__global__ __launch_bounds__(1024, 4) void stageB(
    const unsigned* __restrict__ Aw,
    const unsigned short* __restrict__ hT,
    const float* __restrict__ exps, const float* __restrict__ exps2,
    const float* __restrict__ expd, const float* __restrict__ expd2,
    const float* __restrict__ bias, const float* __restrict__ mz,
    float* __restrict__ out)
{
  __shared__ float ed_l[NH * NN];        // 32 KB
  __shared__ float e2_l[NH * NN];        // 32 KB
  __shared__ unsigned mask_l[32 * 33];   // 4.2 KB, pad 33 vs bank stride
  __shared__ float oacc[32 * 65];        // pad 65: conflict-free atomics
  const int t = threadIdx.x, b = blockIdx.y, n0 = blockIdx.x * 32;
  const int h = (t >> 6) & 7, rg = t >> 9;
  const int lane = t & 63, quad = lane >> 4, l15 = lane & 15;
  const int row = n0 + rg * 16 + l15;

  for (int i = t; i < 32 * 65; i += 1024) oacc[i] = 0.f;
  {                                       // exp-table preload (coalesced)
    const float* s1 = expd  + b * 8192;
    const float* s2 = expd2 + b * 8192;
    *(f32x4*)(ed_l + t * 4)        = *(const f32x4*)(s1 + t * 4);
    *(f32x4*)(ed_l + t * 4 + 4096) = *(const f32x4*)(s1 + t * 4 + 4096);
    *(f32x4*)(e2_l + t * 4)        = *(const f32x4*)(s2 + t * 4);
    *(f32x4*)(e2_l + t * 4 + 4096) = *(const f32x4*)(s2 + t * 4 + 4096);
  }
  mask_l[(t >> 5) * 33 + (t & 31)] = Aw[(b * NN + n0 + (t >> 5)) * 32 + (t & 31)];
  __syncthreads();

  const float Es  = exps [(b * NH + h) * NN + row];
  const float Es2 = exps2[(b * NH + h) * NN + row];
  const unsigned short* pb = hT + (size_t)(b * NH + h) * 65536 + l15 * 32 + quad * 8;
  const float* edh = ed_l + h * NN + quad * 8;
  const float* e2h = e2_l + h * NN + quad * 8;
  const int mrow = (rg * 16 + l15) * 33;

  U8 ones;                                // all-ones B for row sums via MFMA
  #pragma unroll
  for (int j = 0; j < 8; j++) ones.u[j] = 0x3F80;

  // depth-2 panel prefetch
  U8 b0[4], b1[4];
  #pragma unroll
  for (int ss = 0; ss < 4; ss++){
    b0[ss].u = *(const u16x8*)(pb + ss * 512);
    b1[ss].u = *(const u16x8*)(pb + 2048 + ss * 512);
  }

  f32x4 acc[4] = {}, accs = {};

  for (int c = 0; c < 32; c++){
    U8 cur[4];
    #pragma unroll
    for (int ss = 0; ss < 4; ss++){ cur[ss] = b0[ss]; b0[ss] = b1[ss]; }
    if (c + 2 < 32){
      #pragma unroll
      for (int ss = 0; ss < 4; ss++)
        b1[ss].u = *(const u16x8*)(pb + (c + 2) * 2048 + ss * 512);
    }
    const unsigned abyte = mask_l[mrow + c] >> (quad * 8);
    f32x4 d0 = *(const f32x4*)(edh + c * 32);
    f32x4 d1 = *(const f32x4*)(edh + c * 32 + 4);
    f32x4 g0 = *(const f32x4*)(e2h + c * 32);
    f32x4 g1 = *(const f32x4*)(e2h + c * 32 + 4);
    U8 p;
    #pragma unroll
    for (int r = 0; r < 4; r++){
      const int j0 = 2 * r, j1 = 2 * r + 1;
      const float dj0 = (j0 < 4) ? d0[j0] : d1[j0 - 4];
      const float gj0 = (j0 < 4) ? g0[j0] : g1[j0 - 4];
      const float dj1 = (j1 < 4) ? d0[j1] : d1[j1 - 4];
      const float gj1 = (j1 < 4) ? g0[j1] : g1[j1 - 4];
      float e0 = fmaxf(Es * dj0, Es2 * gj0);
      float e1 = fmaxf(Es * dj1, Es2 * gj1);
      e0 = (abyte & (1u << j0)) ? e0 : 0.f;
      e1 = (abyte & (1u << j1)) ? e1 : 0.f;
      p.w[r] = pack_bf16(e0, e1);
    }
    #pragma unroll
    for (int ss = 0; ss < 4; ss++)
      acc[ss] = __builtin_amdgcn_mfma_f32_16x16x32_bf16(p.b, cur[ss].b, acc[ss], 0, 0, 0);
    accs = __builtin_amdgcn_mfma_f32_16x16x32_bf16(p.b, ones.b, accs, 0, 0, 0);
  }

  // accs[i] = full row sum for row rg*16+quad*4+i (all cols identical)
  float inv[4];
  #pragma unroll
  for (int i = 0; i < 4; i++) inv[i] = 0.125f / accs[i];

  #pragma unroll
  for (int ss = 0; ss < 4; ss++)
    #pragma unroll
    for (int i = 0; i < 4; i++)
      atomicAdd(&oacc[(rg * 16 + quad * 4 + i) * 65 + ss * 16 + l15], acc[ss][i] * inv[i]);
  __syncthreads();

  for (int i = t; i < 2048; i += 1024){
    const int r = i >> 6, o = i & 63;
    out[(b * NN + n0 + r) * FO + o] = (oacc[r * 65 + o] + bias[o]) * mz[b * NN + n0 + r];
  }
}

extern "C" void kernel_launch(void* const* d_in, const int* in_sizes, int n_in,
                              void* d_out, int out_size, void* d_ws, size_t ws_size,
                              hipStream_t stream)
{
  (void)in_sizes; (void)n_in; (void)out_size; (void)ws_size;
  const float* x    = (const float*)d_in[0];
  const int*   A    = (const int*)d_in[1];
  const float* mz   = (const float*)d_in[2];
  const float* e_at = (const float*)d_in[4];
  const float* Np   = (const float*)d_in[5];
  const float* w    = (const float*)d_in[6];
  const float* asrc = (const float*)d_in[7];
  const float* adst = (const float*)d_in[8];
  const float* bias = (const float*)d_in[9];
  float* out = (float*)d_out;

  char* ws = (char*)d_ws;
  unsigned short* recx = (unsigned short*)ws;                      // 4 MB
  unsigned short* wBuf = (unsigned short*)(ws + 4194304);          // 256 KB
  unsigned short* hT   = (unsigned short*)(ws + 4456448);          // 8 MB
  float* exps  = (float*)(ws + 12845056);                          // 256 KB
  float* exps2 = (float*)(ws + 13107200);                          // 256 KB
  float* expd  = (float*)(ws + 13369344);                          // 256 KB
  float* expd2 = (float*)(ws + 13631488);                          // 256 KB
  unsigned long long* Abits = (unsigned long long*)(ws + 13893632);// 1 MB

  stage0<<<dim3(1024), dim3(256), 0, stream>>>(x, e_at, Np, w, A, recx, wBuf, Abits);
  stageA<<<dim3(32, 8), dim3(512), 0, stream>>>(recx, wBuf, asrc, adst, hT,
                                                exps, exps2, expd, expd2);
  stageB<<<dim3(32, 8), dim3(1024), 0, stream>>>((const unsigned*)Abits, hT,
                                                 exps, exps2, expd, expd2,
                                                 bias, mz, out);
}